// Round 2
// 12685.820 us; speedup vs baseline: 2.4441x; 2.4441x over previous
//
#include <hip/hip_runtime.h>
#include <math.h>

// Problem dims
#define Bq   128
#define Pp   196
#define ENCC 2048
#define Dd   1024
#define Aa   1024
#define Vv   32000
#define TMx  21
#define CAPq 22

// ---- output layout (floats, concatenated in reference return order) ----
#define O_PRED 0
#define O_CAPS (Bq * TMx * Vv)          // 86016000
#define O_DECL (O_CAPS + Bq * CAPq)
#define O_SORT (O_DECL + Bq)
#define O_RELP (O_SORT + Bq)
#define O_PPOS (O_RELP + Bq * TMx)

// ---- fixed workspace prefix (float units) ----
#define WS_SORT 0                        // int[128]
#define WS_DECL 128                      // int[128]
#define WS_CAPS 256                      // int[128*22]
#define WS_H1   3072
#define WS_C1   (WS_H1 + Bq * Dd)
#define WS_H2   (WS_C1 + Bq * Dd)
#define WS_C2   (WS_H2 + Bq * Dd)
#define WS_GATE (WS_C2 + Bq * Dd)        // 128*2048: pre-loop mean_enc, then gate*awe each step
#define WS_GM   (WS_GATE + Bq * ENCC)    // 128*4096: g_mean = mean @ W1ih[:,2048:].T  (t-invariant)
#define WS_GP   (WS_GM + Bq * 4096)      // split-K partial region (size depends on config)
// scws and att1 offsets computed at runtime in the launcher.

__device__ __forceinline__ float sigm(float x) { return 1.0f / (1.0f + expf(-x)); }

// ---------------- sort + small outputs (1 block, 128 threads) ----------------
__global__ void k_sort(const int* __restrict__ caplens, const int* __restrict__ captions,
                       float* __restrict__ out, int* __restrict__ sort_ind,
                       int* __restrict__ dec_len, int* __restrict__ caps_ws)
{
    __shared__ int lens[Bq];
    __shared__ int sind[Bq];
    const int b = threadIdx.x;
    lens[b] = caplens[b];
    __syncthreads();
    const int myl = lens[b];
    int rank = 0;
    for (int j = 0; j < Bq; ++j) {
        int lj = lens[j];
        rank += (lj > myl) || (lj == myl && j < b);  // stable descending
    }
    sind[rank] = b;
    __syncthreads();
    const int src = sind[b];
    const int dl = lens[src] - 1;
    sort_ind[b] = src;
    dec_len[b]  = dl;
    out[O_DECL + b] = (float)dl;
    out[O_SORT + b] = (float)src;
    for (int t = 0; t < CAPq; ++t) {
        int cv = captions[src * CAPq + t];
        caps_ws[b * CAPq + t] = cv;
        out[O_CAPS + b * CAPq + t] = (float)cv;
    }
    const float dlf = (float)dl;
    for (int t = 0; t < TMx; ++t)
        out[O_RELP + b * TMx + t] = (t < dl) ? ((float)(t + 1)) / dlf : 0.0f;
}

// ---------------- zero h1,c1,h2,c2 (contiguous 4*128*1024 floats) ----------------
__global__ void k_zero(float* __restrict__ p)
{
    int i = blockIdx.x * 256 + threadIdx.x;
    p[i] = 0.0f;
}

// ---------------- mean_enc (into WS_GATE buffer; dead after g_mean GEMM) ----------
__global__ void k_mean(const float* __restrict__ enc, const int* __restrict__ si,
                       float* __restrict__ mean_enc)
{
    const int b = blockIdx.y;
    const int e = blockIdx.x * 256 + threadIdx.x;
    const float* p0 = enc + ((size_t)si[b] * Pp) * ENCC + e;
    float s = 0.0f;
    for (int p = 0; p < Pp; ++p) s += p0[(size_t)p * ENCC];
    mean_enc[b * ENCC + e] = s * (1.0f / (float)Pp);
}

// =======================================================================
// Multi-segment split-K GEMM: M = 128, BN2 = 32 cols/block, BK = 16.
// Virtual K = Ka + Kb + Kc over up to 3 (X, W) segment pairs; W pointers
// are pre-offset to the segment's column base. Segment a may gather rows
// via gidx (emb lookup). Block ks covers virtual range [kb[ks], kb[ks+1]),
// which may span segment boundaries (walked piecewise; all boundaries
// must be multiples of 16).
// For n0 >= nsplit, W is replaced by Wn2 (same ldw as active segment).
// EPI 0: partial store  outp[(ks*128+m)*ldo + n]  (no bias; consumer sums)
// EPI 2: preds epilogue (1 chunk): out[(m*21+t)*32000+n] = mask ? acc+b1 : 0
// =======================================================================
#define BM 64
#define BN 64
#define BK 16
#define BM2 128
#define BN2 32

template<int EPI>
__global__ __launch_bounds__(256)
void gemm_sk(const float* __restrict__ Xa, int ldxa, int Ka, const float* __restrict__ Wa, int ldwa,
             const float* __restrict__ Xb, int ldxb, int Kb, const float* __restrict__ Wb, int ldwb,
             const float* __restrict__ Xc, int ldxc, int Kc, const float* __restrict__ Wc, int ldwc,
             const int* __restrict__ gidx, int gstride,
             const float* __restrict__ Wn2, int nsplit,
             int kb0, int kb1, int kb2, int kb3, int kb4,
             float* __restrict__ outp, int ldo,
             const float* __restrict__ b1, const int* __restrict__ dec_len, int t)
{
    __shared__ float Xs[BK][BM2 + 4];
    __shared__ float Wsh[BK][BN2 + 4];
    const int tid = threadIdx.x;
    const int n0 = blockIdx.x * BN2;
    const int ksb = blockIdx.y;
    const int kv0 = (ksb == 0) ? kb0 : (ksb == 1) ? kb1 : (ksb == 2) ? kb2 : kb3;
    const int kv1 = (ksb == 0) ? kb1 : (ksb == 1) ? kb2 : (ksb == 2) ? kb3 : kb4;

    // staging map: X tile 128x16 = 512 float4 -> 2/thread
    const int xi  = tid * 2;
    const int xr0 = xi >> 2,       xk0 = (xi & 3) << 2;
    const int xr1 = (xi + 1) >> 2, xk1 = ((xi + 1) & 3) << 2;
    // W tile 32x16 = 128 float4 -> threads < 128
    const int wr = tid >> 2, wk = (tid & 3) << 2;
    const int ty = tid >> 3, tx = tid & 7;   // m-quad 0..31, n-quad 0..7

    float acc[4][4] = {};

    int vk = kv0;
    while (vk < kv1) {
        const float* X; int ldx; const float* W; int ldw; int segbase; int segend; bool gat = false;
        if (vk < Ka)           { X = Xa; ldx = ldxa; W = Wa; ldw = ldwa; segbase = 0;       segend = Ka;           gat = (gidx != nullptr); }
        else if (vk < Ka + Kb) { X = Xb; ldx = ldxb; W = Wb; ldw = ldwb; segbase = Ka;      segend = Ka + Kb; }
        else                   { X = Xc; ldx = ldxc; W = Wc; ldw = ldwc; segbase = Ka + Kb; segend = Ka + Kb + Kc; }
        const int pend = (kv1 < segend) ? kv1 : segend;
        const int lk0  = vk - segbase;
        const int plen = pend - vk;

        const int r0 = gat ? gidx[xr0 * gstride] : xr0;
        const int r1 = gat ? gidx[xr1 * gstride] : xr1;
        const float* Xp0 = X + (size_t)r0 * ldx + lk0 + xk0;
        const float* Xp1 = X + (size_t)r1 * ldx + lk0 + xk1;
        const float* Wp  = ((n0 >= nsplit) ? (Wn2 + (size_t)(n0 - nsplit + wr) * ldw)
                                           : (W   + (size_t)(n0 + wr) * ldw)) + lk0 + wk;

        float4 xa4 = *(const float4*)(Xp0);
        float4 xb4 = *(const float4*)(Xp1);
        float4 wv4 = (tid < 128) ? *(const float4*)(Wp) : make_float4(0.f, 0.f, 0.f, 0.f);

        for (int k0 = 0; k0 < plen; k0 += BK) {
            __syncthreads();   // previous tile's readers done
            Xs[xk0 + 0][xr0] = xa4.x; Xs[xk0 + 1][xr0] = xa4.y;
            Xs[xk0 + 2][xr0] = xa4.z; Xs[xk0 + 3][xr0] = xa4.w;
            Xs[xk1 + 0][xr1] = xb4.x; Xs[xk1 + 1][xr1] = xb4.y;
            Xs[xk1 + 2][xr1] = xb4.z; Xs[xk1 + 3][xr1] = xb4.w;
            if (tid < 128) {
                Wsh[wk + 0][wr] = wv4.x; Wsh[wk + 1][wr] = wv4.y;
                Wsh[wk + 2][wr] = wv4.z; Wsh[wk + 3][wr] = wv4.w;
            }
            if (k0 + BK < plen) {   // prefetch next tile (latency hides under compute)
                xa4 = *(const float4*)(Xp0 + k0 + BK);
                xb4 = *(const float4*)(Xp1 + k0 + BK);
                if (tid < 128) wv4 = *(const float4*)(Wp + k0 + BK);
            }
            __syncthreads();
            #pragma unroll
            for (int k = 0; k < BK; ++k) {
                float4 a = *(const float4*)&Xs[k][ty << 2];
                float4 w = *(const float4*)&Wsh[k][tx << 2];
                acc[0][0] += a.x * w.x; acc[0][1] += a.x * w.y; acc[0][2] += a.x * w.z; acc[0][3] += a.x * w.w;
                acc[1][0] += a.y * w.x; acc[1][1] += a.y * w.y; acc[1][2] += a.y * w.z; acc[1][3] += a.y * w.w;
                acc[2][0] += a.z * w.x; acc[2][1] += a.z * w.y; acc[2][2] += a.z * w.z; acc[2][3] += a.z * w.w;
                acc[3][0] += a.w * w.x; acc[3][1] += a.w * w.y; acc[3][2] += a.w * w.z; acc[3][3] += a.w * w.w;
            }
        }
        vk = pend;
    }

    const int mb = ty << 2;
    const int nb = n0 + (tx << 2);
    #pragma unroll
    for (int i = 0; i < 4; ++i) {
        const int m = mb + i;
        float4 v;
        if (EPI == 0) {
            v.x = acc[i][0]; v.y = acc[i][1]; v.z = acc[i][2]; v.w = acc[i][3];
            *(float4*)(outp + ((size_t)(ksb * Bq + m)) * ldo + nb) = v;
        } else {
            const int masked = (t >= dec_len[m]);
            v.x = masked ? 0.0f : acc[i][0] + b1[nb + 0];
            v.y = masked ? 0.0f : acc[i][1] + b1[nb + 1];
            v.z = masked ? 0.0f : acc[i][2] + b1[nb + 2];
            v.w = masked ? 0.0f : acc[i][3] + b1[nb + 3];
            *(float4*)(outp + ((size_t)m * TMx + t) * Vv + nb) = v;
        }
    }
}

// ---------------- att1 = enc_sorted @ enc_att_W.T + b : M=25088, N=1024, K=2048 ----
__global__ __launch_bounds__(256)
void gemm_att1(const float* __restrict__ enc, const float* __restrict__ W,
               const float* __restrict__ bias, const int* __restrict__ si,
               float* __restrict__ out)
{
    __shared__ float Xs[BK][BM + 4];
    __shared__ float Wsh[BK][BN + 4];
    const int tid = threadIdx.x;
    const int tx = tid & 15, ty = tid >> 4;
    const int m0 = blockIdx.y * BM;
    const int n0 = blockIdx.x * BN;
    const int lr = tid >> 2;
    const int lk = (tid & 3) << 2;
    const int m = m0 + lr;
    const int bb = m / Pp;
    const int pp = m - bb * Pp;
    const float* Xrow = enc + ((size_t)si[bb] * Pp + pp) * ENCC;
    const float* Wrow = W + (size_t)(n0 + lr) * ENCC;

    float acc[4][4] = {};
    for (int k0 = 0; k0 < ENCC; k0 += BK) {
        float4 xv = *(const float4*)(Xrow + k0 + lk);
        float4 wv = *(const float4*)(Wrow + k0 + lk);
        __syncthreads();
        Xs[lk + 0][lr] = xv.x; Xs[lk + 1][lr] = xv.y;
        Xs[lk + 2][lr] = xv.z; Xs[lk + 3][lr] = xv.w;
        Wsh[lk + 0][lr] = wv.x; Wsh[lk + 1][lr] = wv.y;
        Wsh[lk + 2][lr] = wv.z; Wsh[lk + 3][lr] = wv.w;
        __syncthreads();
        #pragma unroll
        for (int k = 0; k < BK; ++k) {
            float4 a = *(const float4*)&Xs[k][ty << 2];
            float4 w = *(const float4*)&Wsh[k][tx << 2];
            acc[0][0] += a.x * w.x; acc[0][1] += a.x * w.y; acc[0][2] += a.x * w.z; acc[0][3] += a.x * w.w;
            acc[1][0] += a.y * w.x; acc[1][1] += a.y * w.y; acc[1][2] += a.y * w.z; acc[1][3] += a.y * w.w;
            acc[2][0] += a.z * w.x; acc[2][1] += a.z * w.y; acc[2][2] += a.z * w.z; acc[2][3] += a.z * w.w;
            acc[3][0] += a.w * w.x; acc[3][1] += a.w * w.y; acc[3][2] += a.w * w.z; acc[3][3] += a.w * w.w;
        }
    }
    const int mb = m0 + (ty << 2);
    const int nb = n0 + (tx << 2);
    #pragma unroll
    for (int i = 0; i < 4; ++i) {
        float4 v;
        v.x = acc[i][0] + bias[nb + 0];
        v.y = acc[i][1] + bias[nb + 1];
        v.z = acc[i][2] + bias[nb + 2];
        v.w = acc[i][3] + bias[nb + 3];
        *(float4*)(out + (size_t)(mb + i) * Aa + nb) = v;
    }
}

// ---------------- LSTM cell: sums KS split-K partials (+ optional extra) + biases ----
__global__ void k_cell(const float* __restrict__ gp, int KS, const float* __restrict__ extra,
                       float* __restrict__ h, float* __restrict__ c,
                       const float* __restrict__ bih, const float* __restrict__ bhh)
{
    const int idx = blockIdx.x * 256 + threadIdx.x;   // < 128*1024
    const int b = idx >> 10;
    const int j = idx & 1023;
    float gi = bih[j]        + bhh[j];
    float gf = bih[j + 1024] + bhh[j + 1024];
    float gg = bih[j + 2048] + bhh[j + 2048];
    float go = bih[j + 3072] + bhh[j + 3072];
    for (int ks = 0; ks < KS; ++ks) {
        const float* gr = gp + ((size_t)ks * Bq + b) * 4096;
        gi += gr[j]; gf += gr[j + 1024]; gg += gr[j + 2048]; go += gr[j + 3072];
    }
    if (extra) {
        const float* er = extra + (size_t)b * 4096;
        gi += er[j]; gf += er[j + 1024]; gg += er[j + 2048]; go += er[j + 3072];
    }
    const float cv = c[idx];
    const float c2 = sigm(gf) * cv + sigm(gi) * tanhf(gg);
    const float h2 = sigm(go) * tanhf(c2);
    c[idx] = c2;
    h[idx] = h2;
}

// ---------------- scores: sc[b,p] = tanh(att1[b,p,:]+a2[b,:]) . wf + fb ----------
// grid (4 p-tiles, 128 b). a2 = sum of NP split-K partials + dec_att_b.
__global__ __launch_bounds__(256)
void k_scores(const float* __restrict__ att1, const float* __restrict__ a2gp, int NP,
              const float* __restrict__ dec_att_b,
              const float* __restrict__ wfull, const float* __restrict__ bfull,
              float* __restrict__ scws)
{
    __shared__ float a2s[Aa];
    __shared__ float wfs[Aa];
    const int tid = threadIdx.x;
    const int b = blockIdx.y;
    for (int j = tid; j < Aa; j += 256) {
        float s = dec_att_b[j];
        for (int ks = 0; ks < NP; ++ks) s += a2gp[((size_t)ks * Bq + b) * 3072 + j];
        a2s[j] = s;
        wfs[j] = wfull[j];
    }
    __syncthreads();
    const int wave = tid >> 6, lane = tid & 63;
    const float fb = bfull[0];
    const int p0 = blockIdx.x * 49;
    for (int p = p0 + wave; p < p0 + 49; p += 4) {
        const float* row = att1 + ((size_t)b * Pp + p) * Aa;
        float s = 0.0f;
        for (int k = lane; k < Aa; k += 64) s += tanhf(row[k] + a2s[k]) * wfs[k];
        for (int off = 32; off; off >>= 1) s += __shfl_down(s, off);
        if (lane == 0) scws[b * Pp + p] = s + fb;
    }
}

// ---------------- awe + gate fused: gate[b,e] = sigm(gatelogit)*sum_p alpha*enc ----
// grid (8 e-tiles of 256, 128 b). Softmax over 196 per block.
__global__ __launch_bounds__(256)
void k_awe(const float* __restrict__ scws, const float* __restrict__ a2gp, int NP,
           const float* __restrict__ f_beta_b,
           const float* __restrict__ enc, const int* __restrict__ si,
           float* __restrict__ gateawe)
{
    __shared__ float al[Pp];
    __shared__ float red[256];
    const int tid = threadIdx.x;
    const int b = blockIdx.y;
    const float v = (tid < Pp) ? scws[b * Pp + tid] : -1e30f;
    red[tid] = v; __syncthreads();
    for (int s = 128; s; s >>= 1) { if (tid < s) red[tid] = fmaxf(red[tid], red[tid + s]); __syncthreads(); }
    const float m = red[0]; __syncthreads();
    const float e = (tid < Pp) ? expf(v - m) : 0.0f;
    red[tid] = e; __syncthreads();
    for (int s = 128; s; s >>= 1) { if (tid < s) red[tid] += red[tid + s]; __syncthreads(); }
    const float rden = 1.0f / red[0]; __syncthreads();
    if (tid < Pp) al[tid] = e * rden;
    __syncthreads();

    const int ecol = blockIdx.x * 256 + tid;
    const float* encb = enc + ((size_t)si[b] * Pp) * ENCC + ecol;
    float acc = 0.0f;
    #pragma unroll 4
    for (int p = 0; p < Pp; ++p) acc += al[p] * encb[(size_t)p * ENCC];
    float gl = f_beta_b[ecol];
    for (int ks = 0; ks < NP; ++ks) gl += a2gp[((size_t)ks * Bq + b) * 3072 + 1024 + ecol];
    gateawe[(size_t)b * ENCC + ecol] = sigm(gl) * acc;
}

// ---------------- rpm head: predicted_pos ----------------
__global__ void k_rpm(const float* __restrict__ h2, const float* __restrict__ rpm_W,
                      const int* __restrict__ dec_len, float* __restrict__ out, int t)
{
    const int b = blockIdx.x;
    const int lane = threadIdx.x;
    float s = 0.0f;
    for (int k = lane; k < Dd; k += 64) s += h2[b * Dd + k] * rpm_W[k];
    for (int off = 32; off; off >>= 1) s += __shfl_down(s, off);
    if (lane == 0) {
        float r = sigm(s);
        out[O_PPOS + b * TMx + t] = (t < dec_len[b]) ? r : 0.0f;
    }
}

extern "C" void kernel_launch(void* const* d_in, const int* in_sizes, int n_in,
                              void* d_out, int out_size, void* d_ws, size_t ws_size,
                              hipStream_t stream)
{
    const float* encoder_out = (const float*)d_in[0];
    const int*   captions    = (const int*)d_in[1];
    const int*   caplens     = (const int*)d_in[2];
    const float* emb         = (const float*)d_in[3];
    const float* enc_att_W   = (const float*)d_in[4];
    const float* enc_att_b   = (const float*)d_in[5];
    const float* dec_att_W   = (const float*)d_in[6];
    const float* dec_att_b   = (const float*)d_in[7];
    const float* full_att_W  = (const float*)d_in[8];
    const float* full_att_b  = (const float*)d_in[9];
    const float* f_beta_W    = (const float*)d_in[10];
    const float* f_beta_b    = (const float*)d_in[11];
    const float* l1_Wih      = (const float*)d_in[12];
    const float* l1_Whh      = (const float*)d_in[13];
    const float* l1_bih      = (const float*)d_in[14];
    const float* l1_bhh      = (const float*)d_in[15];
    const float* l2_Wih      = (const float*)d_in[16];
    const float* l2_Whh      = (const float*)d_in[17];
    const float* l2_bih      = (const float*)d_in[18];
    const float* l2_bhh      = (const float*)d_in[19];
    const float* ram_W       = (const float*)d_in[20];
    const float* ram_b       = (const float*)d_in[21];
    const float* rpm_W       = (const float*)d_in[22];

    float* ws  = (float*)d_ws;
    float* out = (float*)d_out;
    int* sort_ind = (int*)(ws + WS_SORT);
    int* dec_len  = (int*)(ws + WS_DECL);
    int* caps_ws  = (int*)(ws + WS_CAPS);
    float* h1    = ws + WS_H1;
    float* c1    = ws + WS_C1;
    float* h2    = ws + WS_H2;
    float* c2    = ws + WS_C2;
    float* gate  = ws + WS_GATE;   // pre-loop: mean_enc; in-loop: gate*awe
    float* gmean = ws + WS_GM;
    float* gp    = ws + WS_GP;     // LSTM-gate partials; aliased by att2/gate partials

    // adaptive split-K width: wide config needs more partial space
    const size_t att1_sz = (size_t)Bq * Pp * Aa;        // 25690112
    const size_t need_big = (size_t)WS_GP + 4 * Bq * 4096 + 25600 + att1_sz;  // ~116.5 MB
    const int big = (ws_size / 4 >= need_big);
    const size_t gpsz = (big ? 4 : 2) * (size_t)Bq * 4096;
    float* scws = ws + WS_GP + gpsz;
    float* att1 = scws + 25600;

    const int nch_g1 = big ? 3 : 2;   // virtual K = 3072 (emb | h2 | h1)
    const int nch_g2 = big ? 4 : 2;   // virtual K = 4096 (gate*awe | h1 | h2)
    const int nch_a2 = big ? 4 : 2;   // virtual K = 1024 (h1)
    const int NOSPLIT = 1 << 30;

    // setup
    k_sort<<<1, 128, 0, stream>>>(caplens, captions, out, sort_ind, dec_len, caps_ws);
    k_zero<<<(4 * Bq * Dd) / 256, 256, 0, stream>>>(h1);   // zeroes h1,c1,h2,c2 (contiguous)
    k_mean<<<dim3(ENCC / 256, Bq), 256, 0, stream>>>(encoder_out, sort_ind, gate);
    // g_mean = mean @ W1ih[:,2048:4096].T  (single chunk, direct store)
    gemm_sk<0><<<dim3(4096 / BN2, 1), 256, 0, stream>>>(
        gate, ENCC, ENCC, l1_Wih + 2048, 4096,
        nullptr, 0, 0, nullptr, 0,
        nullptr, 0, 0, nullptr, 0,
        nullptr, 0, nullptr, NOSPLIT,
        0, ENCC, 0, 0, 0,
        gmean, 4096, nullptr, nullptr, 0);
    gemm_att1<<<dim3(Aa / BN, (Bq * Pp) / BM), 256, 0, stream>>>(encoder_out, enc_att_W, enc_att_b, sort_ind, att1);

    for (int t = 0; t < TMx; ++t) {
        // g1 partials: [emb(e_t) | h2 | h1]  x  [W1ih[:,0:1024] | W1ih[:,1024:2048] | W1hh]
        if (big)
            gemm_sk<0><<<dim3(4096 / BN2, 3), 256, 0, stream>>>(
                emb, Dd, 1024, l1_Wih, 4096,
                h2, Dd, 1024, l1_Wih + 1024, 4096,
                h1, Dd, 1024, l1_Whh, 1024,
                caps_ws + t, CAPq, nullptr, NOSPLIT,
                0, 1024, 2048, 3072, 0,
                gp, 4096, nullptr, nullptr, 0);
        else
            gemm_sk<0><<<dim3(4096 / BN2, 2), 256, 0, stream>>>(
                emb, Dd, 1024, l1_Wih, 4096,
                h2, Dd, 1024, l1_Wih + 1024, 4096,
                h1, Dd, 1024, l1_Whh, 1024,
                caps_ws + t, CAPq, nullptr, NOSPLIT,
                0, 1536, 3072, 0, 0,
                gp, 4096, nullptr, nullptr, 0);
        k_cell<<<(Bq * Dd) / 256, 256, 0, stream>>>(gp, nch_g1, gmean, h1, c1, l1_bih, l1_bhh);
        // att2|gate-logit partials: N=3072, cols<1024 use dec_att_W, cols>=1024 use f_beta_W
        if (big)
            gemm_sk<0><<<dim3(3072 / BN2, 4), 256, 0, stream>>>(
                h1, Dd, 1024, dec_att_W, 1024,
                nullptr, 0, 0, nullptr, 0,
                nullptr, 0, 0, nullptr, 0,
                nullptr, 0, f_beta_W, 1024,
                0, 256, 512, 768, 1024,
                gp, 3072, nullptr, nullptr, 0);
        else
            gemm_sk<0><<<dim3(3072 / BN2, 2), 256, 0, stream>>>(
                h1, Dd, 1024, dec_att_W, 1024,
                nullptr, 0, 0, nullptr, 0,
                nullptr, 0, 0, nullptr, 0,
                nullptr, 0, f_beta_W, 1024,
                0, 512, 1024, 0, 0,
                gp, 3072, nullptr, nullptr, 0);
        k_scores<<<dim3(4, Bq), 256, 0, stream>>>(att1, gp, nch_a2, dec_att_b, full_att_W, full_att_b, scws);
        k_awe<<<dim3(ENCC / 256, Bq), 256, 0, stream>>>(scws, gp, nch_a2, f_beta_b, encoder_out, sort_ind, gate);
        // g2 partials: [gate*awe | h1 | h2] x [W2ih[:,0:2048] | W2ih[:,2048:3072] | W2hh]
        if (big)
            gemm_sk<0><<<dim3(4096 / BN2, 4), 256, 0, stream>>>(
                gate, ENCC, 2048, l2_Wih, 3072,
                h1, Dd, 1024, l2_Wih + 2048, 3072,
                h2, Dd, 1024, l2_Whh, 1024,
                nullptr, 0, nullptr, NOSPLIT,
                0, 1024, 2048, 3072, 4096,
                gp, 4096, nullptr, nullptr, 0);
        else
            gemm_sk<0><<<dim3(4096 / BN2, 2), 256, 0, stream>>>(
                gate, ENCC, 2048, l2_Wih, 3072,
                h1, Dd, 1024, l2_Wih + 2048, 3072,
                h2, Dd, 1024, l2_Whh, 1024,
                nullptr, 0, nullptr, NOSPLIT,
                0, 2048, 4096, 0, 0,
                gp, 4096, nullptr, nullptr, 0);
        k_cell<<<(Bq * Dd) / 256, 256, 0, stream>>>(gp, nch_g2, nullptr, h2, c2, l2_bih, l2_bhh);
        // predictions[:, t, :] = mask ? h2@ram_W.T + ram_b : 0
        gemm_sk<2><<<dim3(Vv / BN2, 1), 256, 0, stream>>>(
            h2, Dd, 1024, ram_W, 1024,
            nullptr, 0, 0, nullptr, 0,
            nullptr, 0, 0, nullptr, 0,
            nullptr, 0, nullptr, NOSPLIT,
            0, 1024, 0, 0, 0,
            out, 0, ram_b, dec_len, t);
        k_rpm<<<Bq, 64, 0, stream>>>(h2, rpm_W, dec_len, out, t);
    }
}

// Round 3
// 7292.899 us; speedup vs baseline: 4.2514x; 1.7395x over previous
//
#include <hip/hip_runtime.h>
#include <hip/hip_fp16.h>
#include <math.h>

// Problem dims
#define Bq   128
#define Pp   196
#define ENCC 2048
#define Dd   1024
#define Aa   1024
#define Vv   32000
#define TMx  21
#define CAPq 22

// ---- output layout (floats, concatenated in reference return order) ----
#define O_PRED 0
#define O_CAPS (Bq * TMx * Vv)          // 86016000
#define O_DECL (O_CAPS + Bq * CAPq)
#define O_SORT (O_DECL + Bq)
#define O_RELP (O_SORT + Bq)
#define O_PPOS (O_RELP + Bq * TMx)

// ---- workspace layout (float units) ----
#define WS_SORT 0                        // int[128]
#define WS_DECL 128                      // int[128]
#define WS_CAPS 256                      // int[128*22]
#define WS_H1   3072
#define WS_C1   (WS_H1 + Bq * Dd)
#define WS_H2   (WS_C1 + Bq * Dd)
#define WS_C2   (WS_H2 + Bq * Dd)
#define WS_GATE (WS_C2 + Bq * Dd)        // 128*2048: pre-loop mean_enc, then gate*awe each step
#define WS_GM   (WS_GATE + Bq * ENCC)    // 128*4096: g_mean = mean @ W1ih[:,2048:].T (t-invariant)
#define WS_GP   (WS_GM + Bq * 4096)      // 4*128*4096 split-K partials
#define WS_SC   (WS_GP + 4 * Bq * 4096)  // 128*196 raw scores (pad 25600)
#define WS_ATT1 (WS_SC + 25600)          // __half[25088*1024] (~51 MB)  total ws ~64 MB

typedef __attribute__((ext_vector_type(8))) short bf16x8;
typedef __attribute__((ext_vector_type(4))) float f32x4;

__device__ __forceinline__ float sigm(float x) { return 1.0f / (1.0f + expf(-x)); }

__device__ __forceinline__ f32x4 mfma16(bf16x8 a, bf16x8 b, f32x4 c) {
    return __builtin_amdgcn_mfma_f32_16x16x32_bf16(a, b, c, 0, 0, 0);
}

// ---------------- sort + small outputs (1 block, 128 threads) ----------------
__global__ void k_sort(const int* __restrict__ caplens, const int* __restrict__ captions,
                       float* __restrict__ out, int* __restrict__ sort_ind,
                       int* __restrict__ dec_len, int* __restrict__ caps_ws)
{
    __shared__ int lens[Bq];
    __shared__ int sind[Bq];
    const int b = threadIdx.x;
    lens[b] = caplens[b];
    __syncthreads();
    const int myl = lens[b];
    int rank = 0;
    for (int j = 0; j < Bq; ++j) {
        int lj = lens[j];
        rank += (lj > myl) || (lj == myl && j < b);  // stable descending
    }
    sind[rank] = b;
    __syncthreads();
    const int src = sind[b];
    const int dl = lens[src] - 1;
    sort_ind[b] = src;
    dec_len[b]  = dl;
    out[O_DECL + b] = (float)dl;
    out[O_SORT + b] = (float)src;
    for (int t = 0; t < CAPq; ++t) {
        int cv = captions[src * CAPq + t];
        caps_ws[b * CAPq + t] = cv;
        out[O_CAPS + b * CAPq + t] = (float)cv;
    }
    const float dlf = (float)dl;
    for (int t = 0; t < TMx; ++t)
        out[O_RELP + b * TMx + t] = (t < dl) ? ((float)(t + 1)) / dlf : 0.0f;
}

// ---------------- zero h1,c1,h2,c2 ----------------
__global__ void k_zero(float* __restrict__ p)
{
    int i = blockIdx.x * 256 + threadIdx.x;
    p[i] = 0.0f;
}

// ---------------- mean_enc ----------------
__global__ void k_mean(const float* __restrict__ enc, const int* __restrict__ si,
                       float* __restrict__ mean_enc)
{
    const int b = blockIdx.y;
    const int e = blockIdx.x * 256 + threadIdx.x;
    const float* p0 = enc + ((size_t)si[b] * Pp) * ENCC + e;
    float s = 0.0f;
    for (int p = 0; p < Pp; ++p) s += p0[(size_t)p * ENCC];
    mean_enc[b * ENCC + e] = s * (1.0f / (float)Pp);
}

// =======================================================================
// MFMA multi-segment split-K GEMM. M = 128 rows/block, BN = 32 cols, K
// slab = 32. fp32 inputs are converted on the fly to bf16 hi/lo pairs
// (x = hi + lo, truncation) staged in LDS in MFMA fragment order; each
// logical product takes 3 MFMAs (hi*hi + hi*lo + lo*hi), err ~2^-16 rel.
// A and B use the SAME (lane-group,elem)->k bijection, so the K-sum is
// correct independent of the hardware's internal k ordering. C/D layout
// (HW-verified): col = lane&15, row = (lane>>4)*4 + reg.
// GATHER: 0 none (blockIdx.y = split-K chunk), 1 = emb row-gather via
// gidx (blockIdx.y = chunk), 2 = att1 enc-gather (blockIdx.y = m-block,
// single chunk).
// EPI: 0 = partial store outp[(ksb*128+m)*ldo+n]; 1 = direct f32 store
// (+opt bias); 2 = preds (mask + bias); 3 = fp16 store (+bias, att1).
// Chunk/segment boundaries must be multiples of 32.
// =======================================================================
#define NOSPLIT (1 << 30)

template<int EPI, int GATHER>
__global__ __launch_bounds__(256)
void gemm_mf(const float* __restrict__ Xa, int ldxa, int Ka, const float* __restrict__ Wa, int ldwa,
             const float* __restrict__ Xb, int ldxb, int Kb, const float* __restrict__ Wb, int ldwb,
             const float* __restrict__ Xc, int ldxc, int Kc_, const float* __restrict__ Wc, int ldwc,
             const int* __restrict__ gidx, int gstride,
             const float* __restrict__ Wn2, int nsplit,
             int kb0, int kb1, int kb2, int kb3, int kb4,
             float* __restrict__ outp, int ldo, __half* __restrict__ outh,
             const float* __restrict__ b1, const int* __restrict__ dec_len, int t)
{
    __shared__ unsigned short XH[8 * 64 * 8];   // [rt][lane][e]  8 KB
    __shared__ unsigned short XL[8 * 64 * 8];
    __shared__ unsigned short WH[2 * 64 * 8];   // [ct][lane][e]  2 KB
    __shared__ unsigned short WL[2 * 64 * 8];

    const int tid = threadIdx.x;
    const int n0  = blockIdx.x * 32;
    const int ksb = (GATHER == 2) ? 0 : blockIdx.y;
    const int m0  = (GATHER == 2) ? blockIdx.y * 128 : 0;
    const int kv0 = (ksb == 0) ? kb0 : (ksb == 1) ? kb1 : (ksb == 2) ? kb2 : kb3;
    const int kv1 = (ksb == 0) ? kb1 : (ksb == 1) ? kb2 : (ksb == 2) ? kb3 : kb4;

    // X staging: thread -> (row, k-half16); 4 float4 = 16 consecutive k
    const int xr = tid >> 1;          // 0..127
    const int xh = tid & 1;           // 0/1 -> k base 0/16
    // W staging: thread -> (n-row, float4 quad)
    const int wn = tid >> 3;          // 0..31
    const int wq = tid & 7;           // k0 = 4*wq
    // wave ids
    const int wid = tid >> 6, lane = tid & 63;

    int xrow_pre = xr;
    if (GATHER == 2) {
        const int g = m0 + xr;
        const int bb = g / Pp;
        xrow_pre = gidx[bb] * Pp + (g - bb * Pp);
    }

    // LDS write offsets (ushort units)
    const int lx  = (xr >> 4) * 512 + ((xr & 15) + 16 * (2 * xh)) * 8;
    const int lw  = (wn >> 4) * 512 + ((wn & 15) + 16 * (wq >> 1)) * 8 + (wq & 1) * 4;

    f32x4 acc[2][2] = {};

    int vk = kv0;
    while (vk < kv1) {
        const float *X, *W; int ldx, ldw, segbase, segend; bool gat = false;
        if (vk < Ka)           { X = Xa; ldx = ldxa; W = Wa; ldw = ldwa; segbase = 0;       segend = Ka;             gat = (GATHER == 1); }
        else if (vk < Ka + Kb) { X = Xb; ldx = ldxb; W = Wb; ldw = ldwb; segbase = Ka;      segend = Ka + Kb; }
        else                   { X = Xc; ldx = ldxc; W = Wc; ldw = ldwc; segbase = Ka + Kb; segend = Ka + Kb + Kc_; }
        const int pend = (kv1 < segend) ? kv1 : segend;
        const int lk0  = vk - segbase;
        const int plen = pend - vk;

        int r;
        if (GATHER == 2) r = xrow_pre;
        else if (gat)    r = gidx[xr * gstride];
        else             r = xr;

        const float* Xp = X + (size_t)r * ldx + lk0 + xh * 16;
        const float* Wbase = (n0 >= nsplit) ? (Wn2 + (size_t)(n0 - nsplit + wn) * ldw)
                                            : (W   + (size_t)(n0 + wn) * ldw);
        const float* Wp = Wbase + lk0 + wq * 4;

        float4 xa0 = *(const float4*)(Xp + 0);
        float4 xa1 = *(const float4*)(Xp + 4);
        float4 xa2 = *(const float4*)(Xp + 8);
        float4 xa3 = *(const float4*)(Xp + 12);
        float4 wv  = *(const float4*)(Wp);

        for (int k0 = 0; k0 < plen; k0 += 32) {
            __syncthreads();   // previous slab's readers done

            // ---- convert X 16 elems -> hi/lo packed words, write LDS ----
            {
                float xs[16];
                *(float4*)&xs[0]  = xa0; *(float4*)&xs[4]  = xa1;
                *(float4*)&xs[8]  = xa2; *(float4*)&xs[12] = xa3;
                unsigned hi[8], lo[8];
                #pragma unroll
                for (int p = 0; p < 8; ++p) {
                    const float a = xs[2 * p], b = xs[2 * p + 1];
                    const unsigned ua = __float_as_uint(a), ub = __float_as_uint(b);
                    const unsigned ha = ua & 0xffff0000u, hb = ub & 0xffff0000u;
                    hi[p] = (ha >> 16) | hb;
                    const float la = a - __uint_as_float(ha);
                    const float lb = b - __uint_as_float(hb);
                    lo[p] = (__float_as_uint(la) >> 16) | (__float_as_uint(lb) & 0xffff0000u);
                }
                *(uint4*)&XH[lx]       = make_uint4(hi[0], hi[1], hi[2], hi[3]);
                *(uint4*)&XH[lx + 128] = make_uint4(hi[4], hi[5], hi[6], hi[7]);
                *(uint4*)&XL[lx]       = make_uint4(lo[0], lo[1], lo[2], lo[3]);
                *(uint4*)&XL[lx + 128] = make_uint4(lo[4], lo[5], lo[6], lo[7]);
            }
            // ---- convert W 4 elems ----
            {
                float wsv[4];
                *(float4*)&wsv[0] = wv;
                unsigned hi[2], lo[2];
                #pragma unroll
                for (int p = 0; p < 2; ++p) {
                    const float a = wsv[2 * p], b = wsv[2 * p + 1];
                    const unsigned ua = __float_as_uint(a), ub = __float_as_uint(b);
                    const unsigned ha = ua & 0xffff0000u, hb = ub & 0xffff0000u;
                    hi[p] = (ha >> 16) | hb;
                    const float la = a - __uint_as_float(ha);
                    const float lb = b - __uint_as_float(hb);
                    lo[p] = (__float_as_uint(la) >> 16) | (__float_as_uint(lb) & 0xffff0000u);
                }
                *(uint2*)&WH[lw] = make_uint2(hi[0], hi[1]);
                *(uint2*)&WL[lw] = make_uint2(lo[0], lo[1]);
            }
            // prefetch next slab into regs (latency hides under MFMA phase)
            if (k0 + 32 < plen) {
                xa0 = *(const float4*)(Xp + k0 + 32);
                xa1 = *(const float4*)(Xp + k0 + 36);
                xa2 = *(const float4*)(Xp + k0 + 40);
                xa3 = *(const float4*)(Xp + k0 + 44);
                wv  = *(const float4*)(Wp + k0 + 32);
            }
            __syncthreads();

            // ---- MFMA: wave owns row-subtiles {2*wid, 2*wid+1}, both col-subtiles ----
            const int xoff = wid * 1024 + lane * 8;
            const int woff = lane * 8;
            bf16x8 ah0 = *(const bf16x8*)&XH[xoff];
            bf16x8 ah1 = *(const bf16x8*)&XH[xoff + 512];
            bf16x8 al0 = *(const bf16x8*)&XL[xoff];
            bf16x8 al1 = *(const bf16x8*)&XL[xoff + 512];
            bf16x8 bh0 = *(const bf16x8*)&WH[woff];
            bf16x8 bh1 = *(const bf16x8*)&WH[woff + 512];
            bf16x8 bl0 = *(const bf16x8*)&WL[woff];
            bf16x8 bl1 = *(const bf16x8*)&WL[woff + 512];

            acc[0][0] = mfma16(ah0, bh0, acc[0][0]);
            acc[0][0] = mfma16(ah0, bl0, acc[0][0]);
            acc[0][0] = mfma16(al0, bh0, acc[0][0]);
            acc[0][1] = mfma16(ah0, bh1, acc[0][1]);
            acc[0][1] = mfma16(ah0, bl1, acc[0][1]);
            acc[0][1] = mfma16(al0, bh1, acc[0][1]);
            acc[1][0] = mfma16(ah1, bh0, acc[1][0]);
            acc[1][0] = mfma16(ah1, bl0, acc[1][0]);
            acc[1][0] = mfma16(al1, bh0, acc[1][0]);
            acc[1][1] = mfma16(ah1, bh1, acc[1][1]);
            acc[1][1] = mfma16(ah1, bl1, acc[1][1]);
            acc[1][1] = mfma16(al1, bh1, acc[1][1]);
        }
        vk = pend;
    }

    // ---- epilogue: C/D layout col=lane&15, row=(lane>>4)*4+reg ----
    #pragma unroll
    for (int i = 0; i < 2; ++i) {
        const int mloc = (2 * wid + i) * 16 + ((lane >> 4) << 2);
        #pragma unroll
        for (int ct = 0; ct < 2; ++ct) {
            const int n = n0 + ct * 16 + (lane & 15);
            #pragma unroll
            for (int j = 0; j < 4; ++j) {
                const int m = mloc + j;
                float v = acc[i][ct][j];
                if (EPI == 0) {
                    outp[((size_t)(ksb * Bq + m)) * ldo + n] = v;
                } else if (EPI == 1) {
                    if (b1) v += b1[n];
                    outp[(size_t)(m0 + m) * ldo + n] = v;
                } else if (EPI == 3) {
                    outh[(size_t)(m0 + m) * ldo + n] = __float2half(v + b1[n]);
                } else {
                    const int masked = (t >= dec_len[m]);
                    outp[((size_t)m * TMx + t) * Vv + n] = masked ? 0.0f : (v + b1[n]);
                }
            }
        }
    }
}

// ---------------- LSTM cell: sums KS split-K partials (+ optional extra) + biases ----
__global__ void k_cell(const float* __restrict__ gp, int KS, const float* __restrict__ extra,
                       float* __restrict__ h, float* __restrict__ c,
                       const float* __restrict__ bih, const float* __restrict__ bhh)
{
    const int idx = blockIdx.x * 256 + threadIdx.x;   // < 128*1024
    const int b = idx >> 10;
    const int j = idx & 1023;
    float gi = bih[j]        + bhh[j];
    float gf = bih[j + 1024] + bhh[j + 1024];
    float gg = bih[j + 2048] + bhh[j + 2048];
    float go = bih[j + 3072] + bhh[j + 3072];
    for (int ks = 0; ks < KS; ++ks) {
        const float* gr = gp + ((size_t)ks * Bq + b) * 4096;
        gi += gr[j]; gf += gr[j + 1024]; gg += gr[j + 2048]; go += gr[j + 3072];
    }
    if (extra) {
        const float* er = extra + (size_t)b * 4096;
        gi += er[j]; gf += er[j + 1024]; gg += er[j + 2048]; go += er[j + 3072];
    }
    const float cv = c[idx];
    const float c2 = sigm(gf) * cv + sigm(gi) * tanhf(gg);
    const float h2 = sigm(go) * tanhf(c2);
    c[idx] = c2;
    h[idx] = h2;
}

// ---------------- scores: sc[b,p] = tanh(att1[b,p,:]+a2[b,:]) . wf + fb ----------
// att1 stored fp16. grid (4 p-tiles, 128 b). a2 = sum of NP partials + dec_att_b.
__global__ __launch_bounds__(256)
void k_scores(const __half* __restrict__ att1, const float* __restrict__ a2gp, int NP,
              const float* __restrict__ dec_att_b,
              const float* __restrict__ wfull, const float* __restrict__ bfull,
              float* __restrict__ scws)
{
    __shared__ float a2s[Aa];
    __shared__ float wfs[Aa];
    const int tid = threadIdx.x;
    const int b = blockIdx.y;
    for (int j = tid; j < Aa; j += 256) {
        float s = dec_att_b[j];
        for (int ks = 0; ks < NP; ++ks) s += a2gp[((size_t)ks * Bq + b) * 3072 + j];
        a2s[j] = s;
        wfs[j] = wfull[j];
    }
    __syncthreads();
    const int wave = tid >> 6, lane = tid & 63;
    const float fb = bfull[0];
    const int p0 = blockIdx.x * 49;
    for (int p = p0 + wave; p < p0 + 49; p += 4) {
        const __half* row = att1 + ((size_t)b * Pp + p) * Aa;
        float s = 0.0f;
        for (int k = lane * 2; k < Aa; k += 128) {
            const float f0 = __half2float(row[k]);
            const float f1 = __half2float(row[k + 1]);
            s += tanhf(f0 + a2s[k]) * wfs[k] + tanhf(f1 + a2s[k + 1]) * wfs[k + 1];
        }
        for (int off = 32; off; off >>= 1) s += __shfl_down(s, off);
        if (lane == 0) scws[b * Pp + p] = s + fb;
    }
}

// ---------------- awe + gate fused: gate[b,e] = sigm(gatelogit)*sum_p alpha*enc ----
__global__ __launch_bounds__(256)
void k_awe(const float* __restrict__ scws, const float* __restrict__ a2gp, int NP,
           const float* __restrict__ f_beta_b,
           const float* __restrict__ enc, const int* __restrict__ si,
           float* __restrict__ gateawe)
{
    __shared__ float al[Pp];
    __shared__ float red[256];
    const int tid = threadIdx.x;
    const int b = blockIdx.y;
    const float v = (tid < Pp) ? scws[b * Pp + tid] : -1e30f;
    red[tid] = v; __syncthreads();
    for (int s = 128; s; s >>= 1) { if (tid < s) red[tid] = fmaxf(red[tid], red[tid + s]); __syncthreads(); }
    const float m = red[0]; __syncthreads();
    const float e = (tid < Pp) ? expf(v - m) : 0.0f;
    red[tid] = e; __syncthreads();
    for (int s = 128; s; s >>= 1) { if (tid < s) red[tid] += red[tid + s]; __syncthreads(); }
    const float rden = 1.0f / red[0]; __syncthreads();
    if (tid < Pp) al[tid] = e * rden;
    __syncthreads();

    const int ecol = blockIdx.x * 256 + tid;
    const float* encb = enc + ((size_t)si[b] * Pp) * ENCC + ecol;
    float acc = 0.0f;
    #pragma unroll 4
    for (int p = 0; p < Pp; ++p) acc += al[p] * encb[(size_t)p * ENCC];
    float gl = f_beta_b[ecol];
    for (int ks = 0; ks < NP; ++ks) gl += a2gp[((size_t)ks * Bq + b) * 3072 + 1024 + ecol];
    gateawe[(size_t)b * ENCC + ecol] = sigm(gl) * acc;
}

// ---------------- rpm head: predicted_pos ----------------
__global__ void k_rpm(const float* __restrict__ h2, const float* __restrict__ rpm_W,
                      const int* __restrict__ dec_len, float* __restrict__ out, int t)
{
    const int b = blockIdx.x;
    const int lane = threadIdx.x;
    float s = 0.0f;
    for (int k = lane; k < Dd; k += 64) s += h2[b * Dd + k] * rpm_W[k];
    for (int off = 32; off; off >>= 1) s += __shfl_down(s, off);
    if (lane == 0) {
        float r = sigm(s);
        out[O_PPOS + b * TMx + t] = (t < dec_len[b]) ? r : 0.0f;
    }
}

extern "C" void kernel_launch(void* const* d_in, const int* in_sizes, int n_in,
                              void* d_out, int out_size, void* d_ws, size_t ws_size,
                              hipStream_t stream)
{
    const float* encoder_out = (const float*)d_in[0];
    const int*   captions    = (const int*)d_in[1];
    const int*   caplens     = (const int*)d_in[2];
    const float* emb         = (const float*)d_in[3];
    const float* enc_att_W   = (const float*)d_in[4];
    const float* enc_att_b   = (const float*)d_in[5];
    const float* dec_att_W   = (const float*)d_in[6];
    const float* dec_att_b   = (const float*)d_in[7];
    const float* full_att_W  = (const float*)d_in[8];
    const float* full_att_b  = (const float*)d_in[9];
    const float* f_beta_W    = (const float*)d_in[10];
    const float* f_beta_b    = (const float*)d_in[11];
    const float* l1_Wih      = (const float*)d_in[12];
    const float* l1_Whh      = (const float*)d_in[13];
    const float* l1_bih      = (const float*)d_in[14];
    const float* l1_bhh      = (const float*)d_in[15];
    const float* l2_Wih      = (const float*)d_in[16];
    const float* l2_Whh      = (const float*)d_in[17];
    const float* l2_bih      = (const float*)d_in[18];
    const float* l2_bhh      = (const float*)d_in[19];
    const float* ram_W       = (const float*)d_in[20];
    const float* ram_b       = (const float*)d_in[21];
    const float* rpm_W       = (const float*)d_in[22];

    float* ws  = (float*)d_ws;
    float* out = (float*)d_out;
    int* sort_ind = (int*)(ws + WS_SORT);
    int* dec_len  = (int*)(ws + WS_DECL);
    int* caps_ws  = (int*)(ws + WS_CAPS);
    float*  h1    = ws + WS_H1;
    float*  c1    = ws + WS_C1;
    float*  h2    = ws + WS_H2;
    float*  c2    = ws + WS_C2;
    float*  gate  = ws + WS_GATE;   // pre-loop: mean_enc; in-loop: gate*awe
    float*  gmean = ws + WS_GM;
    float*  gp    = ws + WS_GP;
    float*  scws  = ws + WS_SC;
    __half* att1h = (__half*)(ws + WS_ATT1);

    // setup
    k_sort<<<1, 128, 0, stream>>>(caplens, captions, out, sort_ind, dec_len, caps_ws);
    k_zero<<<(4 * Bq * Dd) / 256, 256, 0, stream>>>(h1);
    k_mean<<<dim3(ENCC / 256, Bq), 256, 0, stream>>>(encoder_out, sort_ind, gate);
    // g_mean = mean @ W1ih[:,2048:4096].T  (direct f32 store, no bias)
    gemm_mf<1, 0><<<dim3(4096 / 32, 1), 256, 0, stream>>>(
        gate, ENCC, ENCC, l1_Wih + 2048, 4096,
        nullptr, 0, 0, nullptr, 0,
        nullptr, 0, 0, nullptr, 0,
        nullptr, 0, nullptr, NOSPLIT,
        0, ENCC, 0, 0, 0,
        gmean, 4096, nullptr, nullptr, nullptr, 0);
    // att1 (fp16) = enc_sorted @ enc_att_W.T + b : grid (32 n-blocks, 196 m-blocks)
    gemm_mf<3, 2><<<dim3(Aa / 32, (Bq * Pp) / 128), 256, 0, stream>>>(
        encoder_out, ENCC, ENCC, enc_att_W, ENCC,
        nullptr, 0, 0, nullptr, 0,
        nullptr, 0, 0, nullptr, 0,
        sort_ind, 0, nullptr, NOSPLIT,
        0, ENCC, 0, 0, 0,
        nullptr, Aa, att1h, enc_att_b, nullptr, 0);

    for (int t = 0; t < TMx; ++t) {
        // g1 partials: [emb(e_t) | h2 | h1] x [W1ih[:,0:1024] | W1ih[:,1024:2048] | W1hh]
        gemm_mf<0, 1><<<dim3(4096 / 32, 3), 256, 0, stream>>>(
            emb, Dd, 1024, l1_Wih, 4096,
            h2, Dd, 1024, l1_Wih + 1024, 4096,
            h1, Dd, 1024, l1_Whh, 1024,
            caps_ws + t, CAPq, nullptr, NOSPLIT,
            0, 1024, 2048, 3072, 0,
            gp, 4096, nullptr, nullptr, nullptr, 0);
        k_cell<<<(Bq * Dd) / 256, 256, 0, stream>>>(gp, 3, gmean, h1, c1, l1_bih, l1_bhh);
        // att2|gate-logit partials: N=3072 (cols<1024 dec_att_W, >=1024 f_beta_W), 4-way split-K
        gemm_mf<0, 0><<<dim3(3072 / 32, 4), 256, 0, stream>>>(
            h1, Dd, 1024, dec_att_W, 1024,
            nullptr, 0, 0, nullptr, 0,
            nullptr, 0, 0, nullptr, 0,
            nullptr, 0, f_beta_W, 1024,
            0, 256, 512, 768, 1024,
            gp, 3072, nullptr, nullptr, nullptr, 0);
        k_scores<<<dim3(4, Bq), 256, 0, stream>>>(att1h, gp, 4, dec_att_b, full_att_W, full_att_b, scws);
        k_awe<<<dim3(ENCC / 256, Bq), 256, 0, stream>>>(scws, gp, 4, f_beta_b, encoder_out, sort_ind, gate);
        // g2 partials: [gate*awe | h1 | h2] x [W2ih[:,0:2048] | W2ih[:,2048:3072] | W2hh]
        gemm_mf<0, 0><<<dim3(4096 / 32, 4), 256, 0, stream>>>(
            gate, ENCC, 2048, l2_Wih, 3072,
            h1, Dd, 1024, l2_Wih + 2048, 3072,
            h2, Dd, 1024, l2_Whh, 1024,
            nullptr, 0, nullptr, NOSPLIT,
            0, 1024, 2048, 3072, 4096,
            gp, 4096, nullptr, nullptr, nullptr, 0);
        k_cell<<<(Bq * Dd) / 256, 256, 0, stream>>>(gp, 4, nullptr, h2, c2, l2_bih, l2_bhh);
        // predictions[:, t, :] = mask ? h2@ram_W.T + ram_b : 0
        gemm_mf<2, 0><<<dim3(Vv / 32, 1), 256, 0, stream>>>(
            h2, Dd, 1024, ram_W, 1024,
            nullptr, 0, 0, nullptr, 0,
            nullptr, 0, 0, nullptr, 0,
            nullptr, 0, nullptr, NOSPLIT,
            0, 1024, 0, 0, 0,
            out, 0, nullptr, ram_b, dec_len, t);
        k_rpm<<<Bq, 64, 0, stream>>>(h2, rpm_W, dec_len, out, t);
    }
}